// Round 4
// baseline (130.507 us; speedup 1.0000x reference)
//
#include <hip/hip_runtime.h>
#include <hip/hip_bf16.h>
#include <cstdint>

// adknnLoss: N=8192, M=128.
//   A = L*X; B = (X@Wnet + bnet)*X
//   dist[i,j] = ||A_i - B_j||; drum = exp(-dist)
//   pred = (drum@Y)/drum.sum(1); loss = sum((Y-pred)^2)
//
// Round 4:
//  - pairwise: 16 rows/wave, 6 waves/SIMD target (launch_bounds(256,6)),
//    explicit 2-deep register pipeline on B fragments, no LDS, no barriers.
//  - prep: 512 single-wave blocks, 4x8 thread tiles, Wnet streamed from L2,
//    X in LDS, direct swizzled-fragment stores. No big LDS staging.
//  - w = exp(-dist) = 2^(-sqrt(K2*d2)), K2=(log2 e)^2 folded into norms.

#define N_ 8192
#define K2_ 2.0813689810056077f      // (log2 e)^2
#define NEG2K2_ -4.1627379620112154f // -2*(log2 e)^2

typedef __bf16 bf16x8 __attribute__((ext_vector_type(8)));
typedef float  f32x4  __attribute__((ext_vector_type(4)));

// Swizzled fragment layout (A and B operands of mfma_f32_16x16x32_bf16):
//   elem_off(row,k) = (row>>4)*2048 + (k>>5)*512 + ((k>>3)&3)*128 + (row&15)*8 + (k&7)
// Wave fragment load for (group g, ks): base + g*2048 + ks*512 + lane*8
// -> lane-contiguous 16 B/lane global_load_dwordx4.

// pack two fp32 into one dword of RNE bf16; also hand back the rounded floats
__device__ __forceinline__ uint32_t rne2(float f0, float f1, float& r0, float& r1) {
    uint32_t u0 = __float_as_uint(f0), u1 = __float_as_uint(f1);
    uint32_t t0 = u0 + 0x7fffu + ((u0 >> 16) & 1u);
    uint32_t t1 = u1 + 0x7fffu + ((u1 >> 16) & 1u);
    r0 = __uint_as_float(t0 & 0xffff0000u);
    r1 = __uint_as_float(t1 & 0xffff0000u);
    return (t0 >> 16) | (t1 & 0xffff0000u);
}

// ---------------------------------------------------------------------------
// prep: 512 blocks x 64 threads (1 wave), 16 rows/block.
// thread (rg=tid>>4, cg=tid&15): rows rg*4..+3, cols cg*8..+7.
// GEMM: acc[r][e] = sum_c Xs[row][c] * Wnet[c][col]; X tile in LDS (8 KB),
// Wnet streamed (L2-hot 64 KB). Epilogue: a=L*X, b=(acc+bnet)*X, RNE->bf16,
// direct swizzled stores (cg = ks*4+quad so the 8 cols ARE one fragment
// octet), norms via shuffle over the 16 cg-lanes. Zeros sumw/sumwy.
// ---------------------------------------------------------------------------
__global__ __launch_bounds__(64) void prep_kernel(
    const float* __restrict__ L, const float* __restrict__ X,
    const float* __restrict__ Y, const float* __restrict__ Wnet,
    const float* __restrict__ bnet,
    unsigned short* __restrict__ Asw, unsigned short* __restrict__ Bsw,
    float* __restrict__ naS, float2* __restrict__ nbY,
    float* __restrict__ sumw, float* __restrict__ sumwy)
{
    __shared__ float Xs[16][128];  // 8 KB
    const int tid  = threadIdx.x;
    const int row0 = blockIdx.x * 16;
    const int rg   = tid >> 4;
    const int cg   = tid & 15;

    #pragma unroll
    for (int i = 0; i < 8; ++i)
        ((float4*)Xs)[tid + i * 64] =
            ((const float4*)(X + (size_t)row0 * 128))[tid + i * 64];
    if (tid < 16) sumw[row0 + tid] = 0.f;
    else if (tid < 32) sumwy[row0 + tid - 16] = 0.f;
    __syncthreads();

    float acc[4][8];
    #pragma unroll
    for (int r = 0; r < 4; ++r)
        #pragma unroll
        for (int e = 0; e < 8; ++e) acc[r][e] = 0.f;

    #pragma unroll 4
    for (int c = 0; c < 128; ++c) {
        const float4 w0 = *(const float4*)(Wnet + c * 128 + cg * 8);
        const float4 w1 = *(const float4*)(Wnet + c * 128 + cg * 8 + 4);
        const float we[8] = {w0.x, w0.y, w0.z, w0.w, w1.x, w1.y, w1.z, w1.w};
        #pragma unroll
        for (int r = 0; r < 4; ++r) {
            const float xv = Xs[rg * 4 + r][c];
            #pragma unroll
            for (int e = 0; e < 8; ++e)
                acc[r][e] = fmaf(xv, we[e], acc[r][e]);
        }
    }

    const float4 bn0 = *(const float4*)(bnet + cg * 8);
    const float4 bn1 = *(const float4*)(bnet + cg * 8 + 4);
    const float bne[8] = {bn0.x, bn0.y, bn0.z, bn0.w, bn1.x, bn1.y, bn1.z, bn1.w};
    const int ks = cg >> 2, quad = cg & 3;

    float napart[4], nbpart[4];
    #pragma unroll
    for (int r = 0; r < 4; ++r) {
        const int ln  = rg * 4 + r;
        const int row = row0 + ln;
        const float4 x0 = *(const float4*)(&Xs[ln][cg * 8]);
        const float4 x1 = *(const float4*)(&Xs[ln][cg * 8 + 4]);
        const float4 l0 = *(const float4*)(L + (size_t)row * 128 + cg * 8);
        const float4 l1 = *(const float4*)(L + (size_t)row * 128 + cg * 8 + 4);
        const float xe[8] = {x0.x, x0.y, x0.z, x0.w, x1.x, x1.y, x1.z, x1.w};
        const float le[8] = {l0.x, l0.y, l0.z, l0.w, l1.x, l1.y, l1.z, l1.w};
        uint32_t pa[4], pb[4];
        float na_ = 0.f, nb_ = 0.f;
        #pragma unroll
        for (int h = 0; h < 4; ++h) {
            float a0 = le[2 * h] * xe[2 * h];
            float a1 = le[2 * h + 1] * xe[2 * h + 1];
            float b0 = (acc[r][2 * h] + bne[2 * h]) * xe[2 * h];
            float b1 = (acc[r][2 * h + 1] + bne[2 * h + 1]) * xe[2 * h + 1];
            float ra0, ra1, rb0, rb1;
            pa[h] = rne2(a0, a1, ra0, ra1);
            pb[h] = rne2(b0, b1, rb0, rb1);
            na_ = fmaf(ra0, ra0, na_); na_ = fmaf(ra1, ra1, na_);
            nb_ = fmaf(rb0, rb0, nb_); nb_ = fmaf(rb1, rb1, nb_);
        }
        napart[r] = na_; nbpart[r] = nb_;
        size_t off = (size_t)blockIdx.x * 2048 + (size_t)ks * 512
                   + (size_t)quad * 128 + (size_t)ln * 8;
        *(uint4*)(Asw + off) = make_uint4(pa[0], pa[1], pa[2], pa[3]);
        *(uint4*)(Bsw + off) = make_uint4(pb[0], pb[1], pb[2], pb[3]);
    }

    #pragma unroll
    for (int m = 1; m <= 8; m <<= 1) {
        #pragma unroll
        for (int r = 0; r < 4; ++r) {
            napart[r] += __shfl_xor(napart[r], m, 64);
            nbpart[r] += __shfl_xor(nbpart[r], m, 64);
        }
    }
    if (cg == 0) {
        #pragma unroll
        for (int r = 0; r < 4; ++r) {
            int row = row0 + rg * 4 + r;
            naS[row] = K2_ * napart[r];
            nbY[row] = make_float2(K2_ * nbpart[r], Y[row]);
        }
    }
}

// ---------------------------------------------------------------------------
// pairwise: grid (128, 16), 256 thr (4 waves), 16 rows/wave, 512-col chunk
// = 32 groups of 16. No LDS, no barriers. Explicit 2-deep register pipeline
// on B fragments; 6 waves/SIMD target. Pipeline prefetch over-reads up to
// 2 groups past the chunk end -- stays inside d_ws, values unused.
// ---------------------------------------------------------------------------
__global__ __launch_bounds__(256, 6) void pairwise_kernel(
    const unsigned short* __restrict__ Asw, const unsigned short* __restrict__ Bsw,
    const float* __restrict__ naS, const float2* __restrict__ nbY,
    float* __restrict__ sumw, float* __restrict__ sumwy)
{
    const int tid  = threadIdx.x;
    const int wv   = tid >> 6;
    const int lane = tid & 63;
    const int ln16 = lane & 15;
    const int quad = lane >> 4;
    const int i0   = blockIdx.x * 64;
    const int j0   = blockIdx.y * 512;
    const int gA   = (i0 >> 4) + wv;

    bf16x8 afrag[4];
    {
        const unsigned short* ap = Asw + (size_t)gA * 2048 + lane * 8;
        #pragma unroll
        for (int ksi = 0; ksi < 4; ++ksi)
            afrag[ksi] = *(const bf16x8*)(ap + ksi * 512);
    }
    float na[4];
    #pragma unroll
    for (int r = 0; r < 4; ++r)
        na[r] = naS[gA * 16 + quad * 4 + r];

    float accw[4] = {0.f, 0.f, 0.f, 0.f};
    float accwy[4] = {0.f, 0.f, 0.f, 0.f};

    const unsigned short* bbase = Bsw + (size_t)(j0 >> 4) * 2048 + lane * 8;
    const float2* nbb = nbY + j0 + ln16;

    bf16x8 b0[4], b1[4];
    float2 nv0, nv1;
    #pragma unroll
    for (int ksi = 0; ksi < 4; ++ksi) {
        b0[ksi] = *(const bf16x8*)(bbase + ksi * 512);
        b1[ksi] = *(const bf16x8*)(bbase + 2048 + ksi * 512);
    }
    nv0 = nbb[0];
    nv1 = nbb[16];

    for (int ct = 0; ct < 32; ct += 2) {
        // ---- stage 0: compute ct with b0, prefetch ct+2 into b0 ----
        {
            f32x4 s = {0.f, 0.f, 0.f, 0.f};
            #pragma unroll
            for (int ksi = 0; ksi < 4; ++ksi)
                s = __builtin_amdgcn_mfma_f32_16x16x32_bf16(afrag[ksi], b0[ksi], s, 0, 0, 0);
            const unsigned short* bp = bbase + (size_t)(ct + 2) * 2048;
            const float yj = nv0.y, nb = nv0.x;
            #pragma unroll
            for (int ksi = 0; ksi < 4; ++ksi)
                b0[ksi] = *(const bf16x8*)(bp + ksi * 512);
            nv0 = nbb[(ct + 2) * 16];
            #pragma unroll
            for (int r = 0; r < 4; ++r) {
                float d2 = fmaf(NEG2K2_, s[r], na[r] + nb);
                d2 = fmaxf(d2, 0.f);
                float w = __builtin_amdgcn_exp2f(-__builtin_amdgcn_sqrtf(d2));
                accw[r] += w;
                accwy[r] = fmaf(w, yj, accwy[r]);
            }
        }
        // ---- stage 1: compute ct+1 with b1, prefetch ct+3 into b1 ----
        {
            f32x4 s = {0.f, 0.f, 0.f, 0.f};
            #pragma unroll
            for (int ksi = 0; ksi < 4; ++ksi)
                s = __builtin_amdgcn_mfma_f32_16x16x32_bf16(afrag[ksi], b1[ksi], s, 0, 0, 0);
            const unsigned short* bp = bbase + (size_t)(ct + 3) * 2048;
            const float yj = nv1.y, nb = nv1.x;
            #pragma unroll
            for (int ksi = 0; ksi < 4; ++ksi)
                b1[ksi] = *(const bf16x8*)(bp + ksi * 512);
            nv1 = nbb[(ct + 3) * 16];
            #pragma unroll
            for (int r = 0; r < 4; ++r) {
                float d2 = fmaf(NEG2K2_, s[r], na[r] + nb);
                d2 = fmaxf(d2, 0.f);
                float w = __builtin_amdgcn_exp2f(-__builtin_amdgcn_sqrtf(d2));
                accw[r] += w;
                accwy[r] = fmaf(w, yj, accwy[r]);
            }
        }
    }

    // reduce over the 16 column-lanes, one atomic per row
    #pragma unroll
    for (int r = 0; r < 4; ++r) {
        float w  = accw[r];
        float wy = accwy[r];
        #pragma unroll
        for (int m = 1; m <= 8; m <<= 1) {
            w  += __shfl_xor(w,  m, 64);
            wy += __shfl_xor(wy, m, 64);
        }
        if (ln16 == 0) {
            int row = i0 + wv * 16 + quad * 4 + r;
            atomicAdd(&sumw[row],  w);
            atomicAdd(&sumwy[row], wy);
        }
    }
}

// ---------------------------------------------------------------------------
__global__ __launch_bounds__(1024) void finish_kernel(
    const float* __restrict__ Y, const float* __restrict__ sumw,
    const float* __restrict__ sumwy, float* __restrict__ out)
{
    __shared__ float red[16];
    const int tid = threadIdx.x;
    float acc = 0.f;
    #pragma unroll
    for (int i = 0; i < 2; ++i) {
        int idx = tid + i * 1024;
        float4 w4  = ((const float4*)sumw)[idx];
        float4 wy4 = ((const float4*)sumwy)[idx];
        float4 y4  = ((const float4*)Y)[idx];
        const float we[4]  = {w4.x, w4.y, w4.z, w4.w};
        const float wye[4] = {wy4.x, wy4.y, wy4.z, wy4.w};
        const float ye[4]  = {y4.x, y4.y, y4.z, y4.w};
        #pragma unroll
        for (int e = 0; e < 4; ++e) {
            float pred = wye[e] * __builtin_amdgcn_rcpf(we[e]);
            float d = ye[e] - pred;
            acc = fmaf(d, d, acc);
        }
    }
    #pragma unroll
    for (int m = 1; m < 64; m <<= 1) acc += __shfl_xor(acc, m, 64);
    if ((tid & 63) == 0) red[tid >> 6] = acc;
    __syncthreads();
    if (tid < 64) {
        float v = (tid < 16) ? red[tid] : 0.f;
        #pragma unroll
        for (int m = 1; m < 16; m <<= 1) v += __shfl_xor(v, m, 64);
        if (tid == 0) out[0] = v;
    }
}

// ---------------------------------------------------------------------------
extern "C" void kernel_launch(void* const* d_in, const int* in_sizes, int n_in,
                              void* d_out, int out_size, void* d_ws, size_t ws_size,
                              hipStream_t stream)
{
    const float* L    = (const float*)d_in[0];
    const float* X    = (const float*)d_in[1];
    const float* Y    = (const float*)d_in[2];
    const float* Wnet = (const float*)d_in[3];
    const float* bnet = (const float*)d_in[4];
    float* out = (float*)d_out;

    // ws: Asw 2MB | Bsw 2MB | naS 32KB | nbY 64KB | sumw 32KB | sumwy 32KB
    char* ws = (char*)d_ws;
    unsigned short* Asw = (unsigned short*)(ws);
    unsigned short* Bsw = (unsigned short*)(ws + (size_t)2 * 1024 * 1024);
    float*  naS   = (float*) (ws + (size_t)4 * 1024 * 1024);
    float2* nbYp  = (float2*)(ws + (size_t)4 * 1024 * 1024 + 32 * 1024);
    float*  sumw  = (float*) (ws + (size_t)4 * 1024 * 1024 + 96 * 1024);
    float*  sumwy = (float*) (ws + (size_t)4 * 1024 * 1024 + 128 * 1024);

    prep_kernel<<<N_ / 16, 64, 0, stream>>>(L, X, Y, Wnet, bnet,
                                            Asw, Bsw, naS, nbYp, sumw, sumwy);
    pairwise_kernel<<<dim3(N_ / 64, 16), 256, 0, stream>>>(Asw, Bsw, naS, nbYp,
                                                           sumw, sumwy);
    finish_kernel<<<1, 1024, 0, stream>>>(Y, sumw, sumwy, out);
}